// Round 1
// baseline (34736.960 us; speedup 1.0000x reference)
//
#include <hip/hip_runtime.h>
#include <cstdint>
#include <cstddef>

#define TSTEPS 512
#define INP    24
#define HID    128
#define G4     512   // 4*HID
#define BB     4     // batch elems per block

// Fast, overflow-safe activations (rel err ~1e-6; threshold is 2e-3).
__device__ __forceinline__ float sigm_f(float v) {
    // 1/(1+exp(-v)); exp never negative -> no NaN, correct saturation.
    return 1.0f / (1.0f + __expf(-v));
}
__device__ __forceinline__ float tanh_f(float v) {
    // tanh(|v|) = (1-e)/(1+e), e = exp(-2|v|) <= 1 -> no overflow ever.
    float a = fabsf(v);
    float e = __expf(-2.0f * a);
    float r = (1.0f - e) / (1.0f + e);
    return v < 0.0f ? -r : r;
}

// One block = 4 batch elements, persistent over all 512 timesteps.
// Thread t (0..511) owns gate row t: W_hh row in 128 VGPRs, W_ih row in 24.
// h lives in LDS (broadcast reads); c lives in a register of the update thread.
__global__ __launch_bounds__(512, 2) void lstm_fused(
    const float* __restrict__ x,      // [B, T, 24]
    const float* __restrict__ addin,  // [B, 2]
    const float* __restrict__ W_ih,   // [512, 24]
    const float* __restrict__ W_hh,   // [512, 128]
    const float* __restrict__ b_ih,   // [512]
    const float* __restrict__ b_hh,   // [512]
    const float* __restrict__ W1,     // [64, 130]
    const float* __restrict__ b1,     // [64]
    const float* __restrict__ W2,     // [3, 64]
    const float* __restrict__ b2,     // [3]
    float* __restrict__ out)          // [B, 3]
{
    __shared__ __align__(16) float h_s[BB][HID];     // 2 KB
    __shared__ float gates_s[BB][G4];                // 8 KB, [b][row]: CF writes+reads
    __shared__ float z_s[BB][64];                    // 1 KB (FC hidden)

    const int t  = threadIdx.x;        // gate row id 0..511
    const int b0 = blockIdx.x * BB;    // batch base
    const int gt = t >> 7;             // gate type: 0=i 1=f 2=g 3=o (wave-uniform)
    const int uj = t & 127;            // as update thread: j = t&127, b = t>>7
    const int ub = gt;

    // ---- one-time weight load into registers ----
    float4 wih[6];
    #pragma unroll
    for (int i = 0; i < 6; ++i)
        wih[i] = ((const float4*)(W_ih + t * INP))[i];
    float4 whh[32];
    #pragma unroll
    for (int i = 0; i < 32; ++i)
        whh[i] = ((const float4*)(W_hh + t * HID))[i];
    const float bias = b_ih[t] + b_hh[t];

    // ---- init state ----
    h_s[t >> 7][t & 127] = 0.0f;
    float c_reg = 0.0f;
    __syncthreads();

    // ---- recurrence ----
    for (int ts = 0; ts < TSTEPS; ++ts) {
        float acc[BB];
        #pragma unroll
        for (int b = 0; b < BB; ++b) {
            // input projection: x[b0+b, ts, 0..23] (16B-aligned: 24 floats = 96 B)
            const float4* xp = (const float4*)(x + ((size_t)(b0 + b) * TSTEPS + ts) * INP);
            float a = bias;
            #pragma unroll
            for (int i = 0; i < 6; ++i) {
                float4 xv = xp[i];
                a += wih[i].x * xv.x + wih[i].y * xv.y
                   + wih[i].z * xv.z + wih[i].w * xv.w;
            }
            // recurrent projection: broadcast reads of h_s[b][*]
            const float4* hp = (const float4*)h_s[b];
            #pragma unroll
            for (int k = 0; k < 32; ++k) {
                float4 hv = hp[k];
                a += whh[k].x * hv.x + whh[k].y * hv.y
                   + whh[k].z * hv.z + whh[k].w * hv.w;
            }
            acc[b] = a;
        }
        // activate (wave-uniform branch on gate type) and publish
        #pragma unroll
        for (int b = 0; b < BB; ++b) {
            float v = (gt == 2) ? tanh_f(acc[b]) : sigm_f(acc[b]);
            gates_s[b][t] = v;   // lane-consecutive -> conflict-free
        }
        __syncthreads();
        // cell update: this thread handles (batch ub, hidden unit uj)
        {
            float iv = gates_s[ub][uj];
            float fv = gates_s[ub][128 + uj];
            float gv = gates_s[ub][256 + uj];
            float ov = gates_s[ub][384 + uj];
            c_reg = fv * c_reg + iv * gv;
            h_s[ub][uj] = ov * tanh_f(c_reg);
        }
        __syncthreads();
    }

    // ---- FC head: relu(concat(h, addin)) @ W1^T + b1 -> relu -> @ W2^T + b2 ----
    if (t < 256) {
        const int b = t >> 6, u = t & 63;
        const float* w = W1 + u * 130;
        float a = b1[u];
        #pragma unroll 16
        for (int k = 0; k < 128; ++k)
            a += fmaxf(h_s[b][k], 0.0f) * w[k];
        const float a0 = addin[(size_t)(b0 + b) * 2 + 0];
        const float a1 = addin[(size_t)(b0 + b) * 2 + 1];
        a += fmaxf(a0, 0.0f) * w[128] + fmaxf(a1, 0.0f) * w[129];
        z_s[b][u] = fmaxf(a, 0.0f);   // relu before second linear
    }
    __syncthreads();
    if (t < 12) {
        const int b = t / 3, o = t - 3 * b;
        const float* w = W2 + o * 64;
        float a = b2[o];
        #pragma unroll
        for (int k = 0; k < 64; ++k)
            a += z_s[b][k] * w[k];
        out[(size_t)(b0 + b) * 3 + o] = a;
    }
}

extern "C" void kernel_launch(void* const* d_in, const int* in_sizes, int n_in,
                              void* d_out, int out_size, void* d_ws, size_t ws_size,
                              hipStream_t stream) {
    const float* x     = (const float*)d_in[0];
    const float* addin = (const float*)d_in[1];
    const float* W_ih  = (const float*)d_in[2];
    const float* W_hh  = (const float*)d_in[3];
    const float* b_ih  = (const float*)d_in[4];
    const float* b_hh  = (const float*)d_in[5];
    const float* W1    = (const float*)d_in[6];
    const float* b1    = (const float*)d_in[7];
    const float* W2    = (const float*)d_in[8];
    const float* b2    = (const float*)d_in[9];
    float* outp        = (float*)d_out;

    const int B = in_sizes[0] / (TSTEPS * INP);   // 1024
    const int grid = B / BB;                      // 256 blocks (1 per CU)

    lstm_fused<<<grid, 512, 0, stream>>>(x, addin, W_ih, W_hh, b_ih, b_hh,
                                         W1, b1, W2, b2, outp);
}

// Round 2
// 5361.558 us; speedup vs baseline: 6.4789x; 6.4789x over previous
//
#include <hip/hip_runtime.h>
#include <cstdint>
#include <cstddef>

#define TSTEPS 512
#define INP    24
#define HID    128
#define BB     4     // batch elems per block

// Fast, overflow-safe activations (rel err ~1e-6; threshold is 2e-3).
__device__ __forceinline__ float sigm_f(float v) {
    return 1.0f / (1.0f + __expf(-v));
}
__device__ __forceinline__ float tanh_f(float v) {
    float a = fabsf(v);
    float e = __expf(-2.0f * a);
    float r = (1.0f - e) / (1.0f + e);
    return v < 0.0f ? -r : r;
}

// 1024 threads/block, 4 batch elems/block, persistent over 512 timesteps.
// Thread layout: wave w (0..15), lane l (0..63); quarter q = l>>4, qi = l&15.
// Row-pair rp = w*16+qi (0..255): thread owns k-quarter [q*32, q*32+32) of
// W_hh rows rp and rp+256 (64 VGPRs) + x-proj cols [q*8, q*8+8) (q<3, 16 VGPRs).
// Designed for the structural 128-VGPR cap at 16 waves/CU (R1 spilled at ~200).
__global__ __launch_bounds__(1024, 4) void lstm_fused(
    const float* __restrict__ x,      // [B, T, 24]
    const float* __restrict__ addin,  // [B, 2]
    const float* __restrict__ W_ih,   // [512, 24]
    const float* __restrict__ W_hh,   // [512, 128]
    const float* __restrict__ b_ih,   // [512]
    const float* __restrict__ b_hh,   // [512]
    const float* __restrict__ W1,     // [64, 130]
    const float* __restrict__ b1,     // [64]
    const float* __restrict__ W2,     // [3, 64]
    const float* __restrict__ b2,     // [3]
    float* __restrict__ out)          // [B, 3]
{
    __shared__ __align__(16) float h_s[BB][HID];   // 2 KB
    __shared__ float part_s[4][BB][512];           // 32 KB: [quarter][b][gate-row]
    __shared__ float z_s[BB][64];                  // 1 KB

    const int t    = threadIdx.x;
    const int lane = t & 63;
    const int wv   = t >> 6;        // 0..15
    const int q    = lane >> 4;     // k-quarter 0..3 (wave-uniform per 16 lanes)
    const int qi   = lane & 15;
    const int rp   = wv * 16 + qi;  // 0..255
    const int r0   = rp, r1 = rp + 256;
    const int b0   = blockIdx.x * BB;

    // ---- one-time weight load: 2 rows x 32-float quarter = 64 VGPRs ----
    float4 whh[2][8];
    #pragma unroll
    for (int c = 0; c < 8; ++c) {
        whh[0][c] = ((const float4*)(W_hh + r0 * HID + q * 32))[c];
        whh[1][c] = ((const float4*)(W_hh + r1 * HID + q * 32))[c];
    }
    // x-projection slice: cols [q*8, q*8+8) for q<3; q==3 carries the bias.
    float4 xw[2][2] = {};
    if (q < 3) {
        xw[0][0] = ((const float4*)(W_ih + r0 * INP + q * 8))[0];
        xw[0][1] = ((const float4*)(W_ih + r0 * INP + q * 8))[1];
        xw[1][0] = ((const float4*)(W_ih + r1 * INP + q * 8))[0];
        xw[1][1] = ((const float4*)(W_ih + r1 * INP + q * 8))[1];
    }
    const float bias0 = b_ih[r0] + b_hh[r0];
    const float bias1 = b_ih[r1] + b_hh[r1];

    // ---- init state ----
    if (t < 512) h_s[t >> 7][t & 127] = 0.0f;
    float c_reg = 0.0f;   // cell state owned by update threads t<512
    __syncthreads();

    // ---- recurrence ----
    for (int ts = 0; ts < TSTEPS; ++ts) {
        float acc0[BB], acc1[BB];
        #pragma unroll
        for (int b = 0; b < BB; ++b) {
            acc0[b] = (q == 3) ? bias0 : 0.0f;
            acc1[b] = (q == 3) ? bias1 : 0.0f;
        }
        // input projection (q<3): 8 cols each
        if (q < 3) {
            #pragma unroll
            for (int b = 0; b < BB; ++b) {
                const float4* xp = (const float4*)(x + ((size_t)(b0 + b) * TSTEPS + ts) * INP + q * 8);
                float4 xa = xp[0], xb = xp[1];
                acc0[b] += xw[0][0].x * xa.x + xw[0][0].y * xa.y + xw[0][0].z * xa.z + xw[0][0].w * xa.w
                         + xw[0][1].x * xb.x + xw[0][1].y * xb.y + xw[0][1].z * xb.z + xw[0][1].w * xb.w;
                acc1[b] += xw[1][0].x * xa.x + xw[1][0].y * xa.y + xw[1][0].z * xa.z + xw[1][0].w * xa.w
                         + xw[1][1].x * xb.x + xw[1][1].y * xb.y + xw[1][1].z * xb.z + xw[1][1].w * xb.w;
            }
        }
        // recurrent projection: broadcast h reads, chunk order rotated by
        // quarter so the 4 quarter-groups of a wave hit disjoint banks.
        #pragma unroll
        for (int b = 0; b < BB; ++b) {
            const float4* hp = (const float4*)h_s[b] + q * 8;
            #pragma unroll
            for (int cc = 0; cc < 8; ++cc) {
                const int ch = (cc + q * 2) & 7;
                float4 hv = hp[ch];
                acc0[b] += whh[0][ch].x * hv.x + whh[0][ch].y * hv.y
                         + whh[0][ch].z * hv.z + whh[0][ch].w * hv.w;
                acc1[b] += whh[1][ch].x * hv.x + whh[1][ch].y * hv.y
                         + whh[1][ch].z * hv.z + whh[1][ch].w * hv.w;
            }
        }
        // publish quarter-partials
        #pragma unroll
        for (int b = 0; b < BB; ++b) {
            part_s[q][b][r0] = acc0[b];
            part_s[q][b][r1] = acc1[b];
        }
        __syncthreads();
        // cell update: thread t<512 owns (batch b = t>>7, unit j = t&127)
        if (t < 512) {
            const int b = t >> 7, j = t & 127;
            float gi = part_s[0][b][j]       + part_s[1][b][j]       + part_s[2][b][j]       + part_s[3][b][j];
            float gf = part_s[0][b][128 + j] + part_s[1][b][128 + j] + part_s[2][b][128 + j] + part_s[3][b][128 + j];
            float gg = part_s[0][b][256 + j] + part_s[1][b][256 + j] + part_s[2][b][256 + j] + part_s[3][b][256 + j];
            float go = part_s[0][b][384 + j] + part_s[1][b][384 + j] + part_s[2][b][384 + j] + part_s[3][b][384 + j];
            gi = sigm_f(gi);
            gf = sigm_f(gf);
            gg = tanh_f(gg);
            go = sigm_f(go);
            c_reg = gf * c_reg + gi * gg;
            h_s[b][j] = go * tanh_f(c_reg);
        }
        __syncthreads();
    }

    // ---- FC head: relu(concat(h, addin)) @ W1^T + b1 -> relu -> @ W2^T + b2 ----
    if (t < 256) {
        const int b = t >> 6, u = t & 63;
        const float* w = W1 + u * 130;
        float a = b1[u];
        #pragma unroll 16
        for (int k = 0; k < 128; ++k)
            a += fmaxf(h_s[b][k], 0.0f) * w[k];
        const float a0 = addin[(size_t)(b0 + b) * 2 + 0];
        const float a1 = addin[(size_t)(b0 + b) * 2 + 1];
        a += fmaxf(a0, 0.0f) * w[128] + fmaxf(a1, 0.0f) * w[129];
        z_s[b][u] = fmaxf(a, 0.0f);
    }
    __syncthreads();
    if (t < 12) {
        const int b = t / 3, o = t - 3 * b;
        const float* w = W2 + o * 64;
        float a = b2[o];
        #pragma unroll
        for (int k = 0; k < 64; ++k)
            a += z_s[b][k] * w[k];
        out[(size_t)(b0 + b) * 3 + o] = a;
    }
}

extern "C" void kernel_launch(void* const* d_in, const int* in_sizes, int n_in,
                              void* d_out, int out_size, void* d_ws, size_t ws_size,
                              hipStream_t stream) {
    const float* x     = (const float*)d_in[0];
    const float* addin = (const float*)d_in[1];
    const float* W_ih  = (const float*)d_in[2];
    const float* W_hh  = (const float*)d_in[3];
    const float* b_ih  = (const float*)d_in[4];
    const float* b_hh  = (const float*)d_in[5];
    const float* W1    = (const float*)d_in[6];
    const float* b1    = (const float*)d_in[7];
    const float* W2    = (const float*)d_in[8];
    const float* b2    = (const float*)d_in[9];
    float* outp        = (float*)d_out;

    const int B = in_sizes[0] / (TSTEPS * INP);   // 1024
    const int grid = B / BB;                      // 256 blocks (1 per CU)

    lstm_fused<<<grid, 1024, 0, stream>>>(x, addin, W_ih, W_hh, b_ih, b_hh,
                                          W1, b1, W2, b2, outp);
}

// Round 3
// 1717.213 us; speedup vs baseline: 20.2287x; 3.1222x over previous
//
#include <hip/hip_runtime.h>
#include <cstdint>
#include <cstddef>

#define TSTEPS 512
#define INP    24
#define HID    128
#define BB     4     // batch elems per block

// Fast, overflow-safe activations (rel err ~1e-6; threshold is 2e-3).
__device__ __forceinline__ float sigm_f(float v) {
    return 1.0f / (1.0f + __expf(-v));
}
__device__ __forceinline__ float tanh_f(float v) {
    float a = fabsf(v);
    float e = __expf(-2.0f * a);
    float r = (1.0f - e) / (1.0f + e);
    return v < 0.0f ? -r : r;
}
__device__ __forceinline__ float dot4(float4 a, float4 b) {
    return a.x * b.x + a.y * b.y + a.z * b.z + a.w * b.w;
}

// 1024 threads/block, BB=4 batches/block, persistent over 512 timesteps.
// Wave w (0..15), lane l; quarter q = l>>4 (k-slice [q*32,q*32+32)), qi = l&15.
// Thread owns rows r0 = w*16+qi and r0+256 (k-quarter each) => 64 weight VGPRs.
//
// LESSONS ENCODED HERE:
//  - R1: >128 VGPRs at 16 waves/CU spills to scratch (67 GB writes). Design for 128.
//  - R2: ANY runtime index into a per-thread array (even wave-structured like q)
//    demotes it to memory; read-only arrays become global re-fetch (17 GB).
//    => every weight-array index below is compile-time static.
//  - Bank conflicts on h broadcast are fixed in the LDS LAYOUT: per-batch h is 4
//    sections of 32 floats at stride 40 (160 B, float4-aligned). Section q begins
//    at bank 8q, chunk cc at banks (8q+4cc)%32 -> the 4 distinct broadcast
//    addresses of one wave ds_read_b128 hit disjoint banks.
__global__ __launch_bounds__(1024, 4) __attribute__((amdgpu_waves_per_eu(4, 4)))
void lstm_fused(
    const float* __restrict__ x,      // [B, T, 24]
    const float* __restrict__ addin,  // [B, 2]
    const float* __restrict__ W_ih,   // [512, 24]
    const float* __restrict__ W_hh,   // [512, 128]
    const float* __restrict__ b_ih,   // [512]
    const float* __restrict__ b_hh,   // [512]
    const float* __restrict__ W1,     // [64, 130]
    const float* __restrict__ b1,     // [64]
    const float* __restrict__ W2,     // [3, 64]
    const float* __restrict__ b2,     // [3]
    float* __restrict__ out)          // [B, 3]
{
    __shared__ __align__(16) float h_s[BB * 160];            // skewed h, 2.5 KB
    __shared__ __align__(16) float part_s[BB * 4 * HID * 4]; // [b][g][j][q], 32 KB
    __shared__ float z_s[BB][64];                            // 1 KB

    const int t    = threadIdx.x;
    const int lane = t & 63;
    const int wv   = t >> 6;        // 0..15
    const int q    = lane >> 4;     // k-quarter 0..3
    const int qi   = lane & 15;
    const int r0   = wv * 16 + qi;  // 0..255; second row is r0+256
    const int b0   = blockIdx.x * BB;

    // ---- one-time weight load (all static indexing) ----
    float4 whh0[8], whh1[8];
    #pragma unroll
    for (int c = 0; c < 8; ++c) {
        whh0[c] = ((const float4*)(W_hh + r0 * HID + q * 32))[c];
        whh1[c] = ((const float4*)(W_hh + (r0 + 256) * HID + q * 32))[c];
    }
    float4 xw00 = {}, xw01 = {}, xw10 = {}, xw11 = {};
    if (q < 3) {
        const float4* p0 = (const float4*)(W_ih + r0 * INP + q * 8);
        const float4* p1 = (const float4*)(W_ih + (r0 + 256) * INP + q * 8);
        xw00 = p0[0]; xw01 = p0[1];
        xw10 = p1[0]; xw11 = p1[1];
    }
    const float bias0 = b_ih[r0] + b_hh[r0];
    const float bias1 = b_ih[r0 + 256] + b_hh[r0 + 256];

    // gate/j decomposition: rows 0..127=i(g=0), 128..255=f(1), 256..383=g(2), 384..511=o(3)
    const int g0 = r0 >> 7;        // 0 or 1
    const int j0 = r0 & 127;

    // ---- init ----
    if (t < BB * 160) h_s[t] = 0.0f;
    float c_reg = 0.0f;            // cell state, owned by update threads t<512
    __syncthreads();

    // ---- recurrence ----
    for (int ts = 0; ts < TSTEPS; ++ts) {
        #pragma unroll
        for (int b = 0; b < BB; ++b) {
            float a0 = (q == 3) ? bias0 : 0.0f;
            float a1 = (q == 3) ? bias1 : 0.0f;
            if (q < 3) {
                const float4* xp = (const float4*)(x + ((size_t)(b0 + b) * TSTEPS + ts) * INP + q * 8);
                float4 xa = xp[0], xb = xp[1];
                a0 += dot4(xw00, xa) + dot4(xw01, xb);
                a1 += dot4(xw10, xa) + dot4(xw11, xb);
            }
            const float4* hp = (const float4*)(h_s + b * 160 + q * 40);
            #pragma unroll
            for (int cc = 0; cc < 8; ++cc) {     // static index only!
                float4 hv = hp[cc];
                a0 += dot4(whh0[cc], hv);
                a1 += dot4(whh1[cc], hv);
            }
            // partial writes: [b][g][j][q]; within a wave banks are hit 2x -> free
            part_s[((b * 4 + g0) * HID + j0) * 4 + q]     = a0;
            part_s[((b * 4 + g0 + 2) * HID + j0) * 4 + q] = a1;
        }
        __syncthreads();
        // cell update: thread t<512 owns (b = t>>7, j = t&127); one float4 per gate
        if (t < 512) {
            const int b = t >> 7, j = t & 127;
            const float4* p4 = (const float4*)part_s;
            float4 pi = p4[(b * 4 + 0) * HID + j];
            float4 pf = p4[(b * 4 + 1) * HID + j];
            float4 pg = p4[(b * 4 + 2) * HID + j];
            float4 po = p4[(b * 4 + 3) * HID + j];
            float gi = sigm_f(pi.x + pi.y + pi.z + pi.w);
            float gf = sigm_f(pf.x + pf.y + pf.z + pf.w);
            float gg = tanh_f(pg.x + pg.y + pg.z + pg.w);
            float go = sigm_f(po.x + po.y + po.z + po.w);
            c_reg = gf * c_reg + gi * gg;
            h_s[b * 160 + (j >> 5) * 40 + (j & 31)] = go * tanh_f(c_reg);
        }
        __syncthreads();
    }

    // ---- FC head ----
    if (t < 256) {
        const int b = t >> 6, u = t & 63;
        const float* w = W1 + u * 130;
        float a = b1[u];
        #pragma unroll 16
        for (int k = 0; k < 128; ++k)
            a += fmaxf(h_s[b * 160 + (k >> 5) * 40 + (k & 31)], 0.0f) * w[k];
        const float a0 = addin[(size_t)(b0 + b) * 2 + 0];
        const float a1 = addin[(size_t)(b0 + b) * 2 + 1];
        a += fmaxf(a0, 0.0f) * w[128] + fmaxf(a1, 0.0f) * w[129];
        z_s[b][u] = fmaxf(a, 0.0f);
    }
    __syncthreads();
    if (t < 12) {
        const int b = t / 3, o = t - 3 * b;
        const float* w = W2 + o * 64;
        float a = b2[o];
        #pragma unroll
        for (int k = 0; k < 64; ++k)
            a += z_s[b][k] * w[k];
        out[(size_t)(b0 + b) * 3 + o] = a;
    }
}

extern "C" void kernel_launch(void* const* d_in, const int* in_sizes, int n_in,
                              void* d_out, int out_size, void* d_ws, size_t ws_size,
                              hipStream_t stream) {
    const float* x     = (const float*)d_in[0];
    const float* addin = (const float*)d_in[1];
    const float* W_ih  = (const float*)d_in[2];
    const float* W_hh  = (const float*)d_in[3];
    const float* b_ih  = (const float*)d_in[4];
    const float* b_hh  = (const float*)d_in[5];
    const float* W1    = (const float*)d_in[6];
    const float* b1    = (const float*)d_in[7];
    const float* W2    = (const float*)d_in[8];
    const float* b2    = (const float*)d_in[9];
    float* outp        = (float*)d_out;

    const int B = in_sizes[0] / (TSTEPS * INP);   // 1024
    const int grid = B / BB;                      // 256 blocks (1 per CU)

    lstm_fused<<<grid, 1024, 0, stream>>>(x, addin, W_ih, W_hh, b_ih, b_hh,
                                          W1, b1, W2, b2, outp);
}

// Round 4
// 927.874 us; speedup vs baseline: 37.4372x; 1.8507x over previous
//
#include <hip/hip_runtime.h>
#include <cstdint>
#include <cstddef>

#define TSTEPS 512
#define INP    24
#define HID    128
#define BB     4      // batch elems per block
#define KTOT   160    // 24 x + 128 h + 8 zero pad -> 5 K-tiles of 32
#define NKT    5
#define VSTR   168    // v[] k-stride in ushorts: 336 B, %128B pattern -> <=2-way banks
#define GSTR   528    // gate_s batch stride in floats: %32==16 -> 2-way (free) on C-dump

typedef __attribute__((ext_vector_type(8))) short short8;   // 8 x bf16 (4 VGPRs)
typedef __attribute__((ext_vector_type(4))) float f32x4;

// Fast, overflow-safe activations (rel err ~1e-6; threshold is 2e-3).
__device__ __forceinline__ float sigm_f(float v) {
    return 1.0f / (1.0f + __expf(-v));
}
__device__ __forceinline__ float tanh_f(float v) {
    float a = fabsf(v);
    float e = __expf(-2.0f * a);
    float r = (1.0f - e) / (1.0f + e);
    return v < 0.0f ? -r : r;
}
// bf16 round-to-nearest-even helpers (manual: values here are small/finite).
__device__ __forceinline__ unsigned short f2bf(float f) {
    unsigned u = __float_as_uint(f);
    return (unsigned short)((u + 0x7fffu + ((u >> 16) & 1u)) >> 16);
}
__device__ __forceinline__ float bf2f(unsigned short h) {
    return __uint_as_float(((unsigned)h) << 16);
}

// ROUND LESSONS ENCODED:
//  R1: compiler may cap VGPRs below launch_bounds allowance and spill to scratch
//      (67 GB HBM writes). Pin occupancy with amdgpu_waves_per_eu(2,2) -> 256-reg
//      budget for 8 waves/CU; watch WRITE_SIZE for betrayal.
//  R2: any runtime-varying index into a per-thread array demotes it to memory
//      (17 GB re-fetch). All A-fragment indices below are compile-time (full unroll).
//  R3: fp32 VALU tops out ~3x slower than needed; MfmaUtil was 0. This round moves
//      the recurrent+input GEMM onto the matrix pipe with split-bf16 (hi/lo, 3
//      products: hi*hi + lo*hi + hi*lo ~ 17-bit mantissa; systematic err ~2^-17).
//
// Layout: gates[512 x 4] = W[512 x 160] @ v[160 x 4] per timestep, where
// v = [x_t(24) | h(128) | 0(8)]. mfma_f32_16x16x32_bf16 tiles; wave w owns
// rows w*64..w*64+63 (4 M-tiles), A-frags persistent in registers.
// mfma A-frag: lane holds A[m=lane&15][k=quad*8+j]; B-frag: B[k=quad*8+j][n=lane&15];
// C/D: col=lane&15, row=quad*4+reg (m89/m91-verified mappings).
__global__ __launch_bounds__(512) __attribute__((amdgpu_waves_per_eu(2, 2)))
void lstm_fused(
    const float* __restrict__ x,      // [B, T, 24]
    const float* __restrict__ addin,  // [B, 2]
    const float* __restrict__ W_ih,   // [512, 24]
    const float* __restrict__ W_hh,   // [512, 128]
    const float* __restrict__ b_ih,   // [512]
    const float* __restrict__ b_hh,   // [512]
    const float* __restrict__ W1,     // [64, 130]
    const float* __restrict__ b1,     // [64]
    const float* __restrict__ W2,     // [3, 64]
    const float* __restrict__ b2,     // [3]
    float* __restrict__ out)          // [B, 3]
{
    __shared__ unsigned short v_hi[16 * VSTR];   // [n][k] bf16 hi; n>=4 stays 0
    __shared__ unsigned short v_lo[16 * VSTR];   // bf16 of residual
    __shared__ float gate_s[BB * GSTR];          // [b][row] mfma preacts
    __shared__ float z_s[BB][64];                // FC hidden

    const int t    = threadIdx.x;      // 512 threads = 8 waves
    const int lane = t & 63;
    const int wv   = t >> 6;           // 0..7
    const int ncol = lane & 15;        // mfma m (A) / n (B,C) index
    const int quad = lane >> 4;        // 0..3
    const int b0   = blockIdx.x * BB;

    // ---- persistent A-fragments: W = [W_ih | W_hh | 0] as bf16 hi/lo ----
    // 4 M-tiles x 5 K-tiles x {hi,lo} x short8 = 160 VGPRs. Static indexing only.
    short8 A_hi[4][NKT], A_lo[4][NKT];
    #pragma unroll
    for (int mi = 0; mi < 4; ++mi) {
        const int row = wv * 64 + mi * 16 + ncol;
        #pragma unroll
        for (int kt = 0; kt < NKT; ++kt) {
            short8 hi, lo;
            #pragma unroll
            for (int j = 0; j < 8; ++j) {
                const int k = kt * 32 + quad * 8 + j;
                float w = 0.0f;
                if (k < INP)            w = W_ih[row * INP + k];
                else if (k < INP + HID) w = W_hh[row * HID + (k - INP)];
                const unsigned short h16 = f2bf(w);
                hi[j] = (short)h16;
                lo[j] = (short)f2bf(w - bf2f(h16));
            }
            A_hi[mi][kt] = hi;
            A_lo[mi][kt] = lo;
        }
    }

    // per-thread update-role constants: (b = t>>7, j = t&127) owns one (batch, unit)
    const int ub = t >> 7, uj = t & 127;
    const float bias_i = b_ih[uj]       + b_hh[uj];
    const float bias_f = b_ih[128 + uj] + b_hh[128 + uj];
    const float bias_g = b_ih[256 + uj] + b_hh[256 + uj];
    const float bias_o = b_ih[384 + uj] + b_hh[384 + uj];
    float c_reg = 0.0f;

    // ---- init: zero v (n>=4 slots and pads stay zero forever), stage x(0) ----
    for (int i = t; i < 16 * VSTR; i += 512) { v_hi[i] = 0; v_lo[i] = 0; }
    __syncthreads();
    if (t < 96) {
        const int xb = t / INP, xk = t - xb * INP;
        const float xv = x[((size_t)(b0 + xb) * TSTEPS) * INP + xk];  // ts=0
        const unsigned short h16 = f2bf(xv);
        v_hi[xb * VSTR + xk] = h16;
        v_lo[xb * VSTR + xk] = f2bf(xv - bf2f(h16));
    }
    __syncthreads();

    // ---- recurrence ----
    for (int ts = 0; ts < TSTEPS; ++ts) {
        // prefetch next x slice (latency hides under mfma phase)
        float x_next = 0.0f;
        int xb = 0, xk = 0;
        if (t < 96) {
            xb = t / INP; xk = t - xb * INP;
            const int tsn = (ts + 1 < TSTEPS) ? ts + 1 : ts;
            x_next = x[((size_t)(b0 + xb) * TSTEPS + tsn) * INP + xk];
        }

        // phase A: B-frag build + mfma + C dump
        f32x4 acc0 = {0.f, 0.f, 0.f, 0.f}, acc1 = acc0, acc2 = acc0, acc3 = acc0;
        #pragma unroll
        for (int kt = 0; kt < NKT; ++kt) {
            const int voff = ncol * VSTR + kt * 32 + quad * 8;
            const short8 bh = *(const short8*)(v_hi + voff);
            const short8 bl = *(const short8*)(v_lo + voff);
            acc0 = __builtin_amdgcn_mfma_f32_16x16x32_bf16(A_hi[0][kt], bh, acc0, 0, 0, 0);
            acc1 = __builtin_amdgcn_mfma_f32_16x16x32_bf16(A_hi[1][kt], bh, acc1, 0, 0, 0);
            acc2 = __builtin_amdgcn_mfma_f32_16x16x32_bf16(A_hi[2][kt], bh, acc2, 0, 0, 0);
            acc3 = __builtin_amdgcn_mfma_f32_16x16x32_bf16(A_hi[3][kt], bh, acc3, 0, 0, 0);
            acc0 = __builtin_amdgcn_mfma_f32_16x16x32_bf16(A_lo[0][kt], bh, acc0, 0, 0, 0);
            acc1 = __builtin_amdgcn_mfma_f32_16x16x32_bf16(A_lo[1][kt], bh, acc1, 0, 0, 0);
            acc2 = __builtin_amdgcn_mfma_f32_16x16x32_bf16(A_lo[2][kt], bh, acc2, 0, 0, 0);
            acc3 = __builtin_amdgcn_mfma_f32_16x16x32_bf16(A_lo[3][kt], bh, acc3, 0, 0, 0);
            acc0 = __builtin_amdgcn_mfma_f32_16x16x32_bf16(A_hi[0][kt], bl, acc0, 0, 0, 0);
            acc1 = __builtin_amdgcn_mfma_f32_16x16x32_bf16(A_hi[1][kt], bl, acc1, 0, 0, 0);
            acc2 = __builtin_amdgcn_mfma_f32_16x16x32_bf16(A_hi[2][kt], bl, acc2, 0, 0, 0);
            acc3 = __builtin_amdgcn_mfma_f32_16x16x32_bf16(A_hi[3][kt], bl, acc3, 0, 0, 0);
        }
        // C dump: only batch columns 0..3 are real; row = wv*64 + mi*16 + quad*4 + reg
        if (ncol < BB) {
            float* gp = gate_s + ncol * GSTR + wv * 64 + quad * 4;
            *(f32x4*)(gp +  0) = acc0;
            *(f32x4*)(gp + 16) = acc1;
            *(f32x4*)(gp + 32) = acc2;
            *(f32x4*)(gp + 48) = acc3;
        }
        __syncthreads();

        // phase B: elementwise cell update (all 512 threads: one (b, j) each)
        {
            const float gi = sigm_f(gate_s[ub * GSTR +       uj] + bias_i);
            const float gf = sigm_f(gate_s[ub * GSTR + 128 + uj] + bias_f);
            const float gg = tanh_f(gate_s[ub * GSTR + 256 + uj] + bias_g);
            const float go = sigm_f(gate_s[ub * GSTR + 384 + uj] + bias_o);
            c_reg = gf * c_reg + gi * gg;
            const float h = go * tanh_f(c_reg);
            const unsigned short h16 = f2bf(h);
            v_hi[ub * VSTR + INP + uj] = h16;
            v_lo[ub * VSTR + INP + uj] = f2bf(h - bf2f(h16));
        }
        // stage x(ts+1)
        if (t < 96) {
            const unsigned short h16 = f2bf(x_next);
            v_hi[xb * VSTR + xk] = h16;
            v_lo[xb * VSTR + xk] = f2bf(x_next - bf2f(h16));
        }
        __syncthreads();
    }

    // ---- FC head: relu(concat(h, addin)) @ W1^T + b1 -> relu -> @ W2^T + b2 ----
    if (t < 256) {
        const int b = t >> 6, u = t & 63;
        const float* w = W1 + u * 130;
        float a = b1[u];
        #pragma unroll 16
        for (int k = 0; k < 128; ++k) {
            const float hv = bf2f(v_hi[b * VSTR + INP + k]) + bf2f(v_lo[b * VSTR + INP + k]);
            a += fmaxf(hv, 0.0f) * w[k];
        }
        const float a0 = addin[(size_t)(b0 + b) * 2 + 0];
        const float a1 = addin[(size_t)(b0 + b) * 2 + 1];
        a += fmaxf(a0, 0.0f) * w[128] + fmaxf(a1, 0.0f) * w[129];
        z_s[b][u] = fmaxf(a, 0.0f);
    }
    __syncthreads();
    if (t < 12) {
        const int b = t / 3, o = t - 3 * b;
        const float* w = W2 + o * 64;
        float a = b2[o];
        #pragma unroll
        for (int k = 0; k < 64; ++k)
            a += z_s[b][k] * w[k];
        out[(size_t)(b0 + b) * 3 + o] = a;
    }
}

extern "C" void kernel_launch(void* const* d_in, const int* in_sizes, int n_in,
                              void* d_out, int out_size, void* d_ws, size_t ws_size,
                              hipStream_t stream) {
    const float* x     = (const float*)d_in[0];
    const float* addin = (const float*)d_in[1];
    const float* W_ih  = (const float*)d_in[2];
    const float* W_hh  = (const float*)d_in[3];
    const float* b_ih  = (const float*)d_in[4];
    const float* b_hh  = (const float*)d_in[5];
    const float* W1    = (const float*)d_in[6];
    const float* b1    = (const float*)d_in[7];
    const float* W2    = (const float*)d_in[8];
    const float* b2    = (const float*)d_in[9];
    float* outp        = (float*)d_out;

    const int B = in_sizes[0] / (TSTEPS * INP);   // 1024
    const int grid = B / BB;                      // 256 blocks (1 per CU)

    lstm_fused<<<grid, 512, 0, stream>>>(x, addin, W_ih, W_hh, b_ih, b_hh,
                                         W1, b1, W2, b2, outp);
}